// Round 1
// baseline (1446.113 us; speedup 1.0000x reference)
//
#include <hip/hip_runtime.h>

#define N_NODES 100000
#define N_EDGES 1600000
#define DIM_IN  128
#define DIM_H   256
#define DIM_C   40

// ---------------- CSR build ----------------

__global__ void k_zero_int(int* __restrict__ p, int n) {
    int i = blockIdx.x * 256 + threadIdx.x;
    if (i < n) p[i] = 0;
}

__global__ void k_hist(const int* __restrict__ dst, int* __restrict__ deg, int e) {
    int i = blockIdx.x * 256 + threadIdx.x;
    if (i < e) atomicAdd(&deg[dst[i]], 1);
}

// inclusive scan within 256-blocks; off[i+1] = partial inclusive scan, bsum[b] = block total
__global__ void k_scan1(const int* __restrict__ deg, int* __restrict__ off,
                        int* __restrict__ bsum, int n) {
    __shared__ int s[256];
    int i = blockIdx.x * 256 + threadIdx.x;
    int v = (i < n) ? deg[i] : 0;
    s[threadIdx.x] = v;
    __syncthreads();
    #pragma unroll
    for (int d = 1; d < 256; d <<= 1) {
        int t = (threadIdx.x >= d) ? s[threadIdx.x - d] : 0;
        __syncthreads();
        s[threadIdx.x] += t;
        __syncthreads();
    }
    if (i < n) off[i + 1] = s[threadIdx.x];
    if (threadIdx.x == 255) bsum[blockIdx.x] = s[255];
}

// single-block inclusive scan of block sums (nb <= 512)
__global__ void k_scan2(int* __restrict__ bsum, int nb) {
    __shared__ int s[512];
    int v = ((int)threadIdx.x < nb) ? bsum[threadIdx.x] : 0;
    s[threadIdx.x] = v;
    __syncthreads();
    #pragma unroll
    for (int d = 1; d < 512; d <<= 1) {
        int t = (threadIdx.x >= d) ? s[threadIdx.x - d] : 0;
        __syncthreads();
        s[threadIdx.x] += t;
        __syncthreads();
    }
    if ((int)threadIdx.x < nb) bsum[threadIdx.x] = s[threadIdx.x];
}

__global__ void k_scan3(int* __restrict__ off, const int* __restrict__ bsum, int n) {
    int i = blockIdx.x * 256 + threadIdx.x;
    if (blockIdx.x > 0 && i < n) off[i + 1] += bsum[blockIdx.x - 1];
    if (i == 0) off[0] = 0;
}

__global__ void k_cursor(const int* __restrict__ off, int* __restrict__ cur, int n) {
    int i = blockIdx.x * 256 + threadIdx.x;
    if (i < n) cur[i] = off[i];
}

__global__ void k_scatter(const int* __restrict__ src, const int* __restrict__ dst,
                          int* __restrict__ cur, int* __restrict__ csr, int e) {
    int i = blockIdx.x * 256 + threadIdx.x;
    if (i < e) {
        int u = dst[i];
        int p = atomicAdd(&cur[u], 1);
        csr[p] = src[i];
    }
}

// ---------------- aggregation: rst[u] = (1+eps)*h[u] + sum_{e:dst=u} h[src[e]] ----------------
// one wave (64 lanes) per node; lane holds D/64 consecutive floats

template <int D>
__global__ void k_agg(const float* __restrict__ h, const int* __restrict__ off,
                      const int* __restrict__ csr, const float* __restrict__ eps_p,
                      float* __restrict__ rst, int n) {
    constexpr int V = D / 64;  // 2 for 128, 4 for 256
    int gid = blockIdx.x * blockDim.x + threadIdx.x;
    int u = gid >> 6;
    int lane = gid & 63;
    if (u >= n) return;

    float acc[V];
    #pragma unroll
    for (int j = 0; j < V; j++) acc[j] = 0.f;

    int r0 = off[u], r1 = off[u + 1];
    for (int r = r0; r < r1; r++) {
        int s = csr[r];
        const float* row = h + (size_t)s * D + lane * V;
        if constexpr (V == 2) {
            float2 v = *(const float2*)row;
            acc[0] += v.x; acc[1] += v.y;
        } else {
            float4 v = *(const float4*)row;
            acc[0] += v.x; acc[1] += v.y; acc[2] += v.z; acc[3] += v.w;
        }
    }
    float ep = 1.0f + eps_p[0];
    const float* xrow = h + (size_t)u * D + lane * V;
    float* orow = rst + (size_t)u * D + lane * V;
    if constexpr (V == 2) {
        float2 xv = *(const float2*)xrow;
        float2 o;
        o.x = ep * xv.x + acc[0];
        o.y = ep * xv.y + acc[1];
        *(float2*)orow = o;
    } else {
        float4 xv = *(const float4*)xrow;
        float4 o;
        o.x = ep * xv.x + acc[0];
        o.y = ep * xv.y + acc[1];
        o.z = ep * xv.z + acc[2];
        o.w = ep * xv.w + acc[3];
        *(float4*)orow = o;
    }
}

// ---------------- fp32 GEMM: C[M,N] = op(A[M,K] @ B[K,N] (+bias)) ----------------
// 128x128 tile, BK=16, 256 threads, 8x8 micro-tile (col fragments at tcol*4 and 64+tcol*4)

__global__ __launch_bounds__(256) void sgemm_kernel(
    const float* __restrict__ A, const float* __restrict__ B,
    const float* __restrict__ bias, float* __restrict__ C,
    int M, int N, int K, int relu)
{
    __shared__ float As[16][132];
    __shared__ float Bs[16][132];
    int tid = threadIdx.x;
    int trow = tid >> 4;   // 0..15
    int tcol = tid & 15;   // 0..15
    int bm = blockIdx.y * 128;
    int bn = blockIdx.x * 128;

    float acc[8][8];
    #pragma unroll
    for (int i = 0; i < 8; i++)
        #pragma unroll
        for (int j = 0; j < 8; j++) acc[i][j] = 0.f;

    for (int k0 = 0; k0 < K; k0 += 16) {
        // stage A tile (128 rows x 16 k), transposed into As[k][m]
        #pragma unroll
        for (int l = 0; l < 2; l++) {
            int idx = tid + l * 256;          // 0..511
            int ar = idx >> 2;                // 0..127
            int ak = (idx & 3) << 2;          // 0,4,8,12
            int gr = bm + ar;
            float4 v = {0.f, 0.f, 0.f, 0.f};
            if (gr < M) v = *(const float4*)(A + (size_t)gr * K + (k0 + ak));
            As[ak + 0][ar] = v.x;
            As[ak + 1][ar] = v.y;
            As[ak + 2][ar] = v.z;
            As[ak + 3][ar] = v.w;
        }
        // stage B tile (16 k x 128 cols)
        #pragma unroll
        for (int l = 0; l < 2; l++) {
            int idx = tid + l * 256;          // 0..511
            int br = idx >> 5;                // 0..15
            int bc = (idx & 31) << 2;         // 0..124
            int gc = bn + bc;
            float4 v = {0.f, 0.f, 0.f, 0.f};
            if (gc <= N - 4) v = *(const float4*)(B + (size_t)(k0 + br) * N + gc);
            *(float4*)&Bs[br][bc] = v;
        }
        __syncthreads();
        #pragma unroll
        for (int kk = 0; kk < 16; kk++) {
            float4 a0 = *(const float4*)&As[kk][trow * 8];
            float4 a1 = *(const float4*)&As[kk][trow * 8 + 4];
            float4 b0 = *(const float4*)&Bs[kk][tcol * 4];
            float4 b1 = *(const float4*)&Bs[kk][tcol * 4 + 64];
            float a[8] = {a0.x, a0.y, a0.z, a0.w, a1.x, a1.y, a1.z, a1.w};
            float b[8] = {b0.x, b0.y, b0.z, b0.w, b1.x, b1.y, b1.z, b1.w};
            #pragma unroll
            for (int i = 0; i < 8; i++)
                #pragma unroll
                for (int j = 0; j < 8; j++)
                    acc[i][j] += a[i] * b[j];
        }
        __syncthreads();
    }

    // epilogue
    #pragma unroll
    for (int i = 0; i < 8; i++) {
        int gr = bm + trow * 8 + i;
        if (gr >= M) continue;
        #pragma unroll
        for (int jh = 0; jh < 2; jh++) {
            int gc = bn + jh * 64 + tcol * 4;
            if (gc <= N - 4) {   // N is always a multiple of 4 here (256, 40)
                float4 o;
                o.x = acc[i][jh * 4 + 0];
                o.y = acc[i][jh * 4 + 1];
                o.z = acc[i][jh * 4 + 2];
                o.w = acc[i][jh * 4 + 3];
                if (bias) {
                    float4 bv = *(const float4*)(bias + gc);
                    o.x += bv.x; o.y += bv.y; o.z += bv.z; o.w += bv.w;
                }
                if (relu) {
                    o.x = fmaxf(o.x, 0.f);
                    o.y = fmaxf(o.y, 0.f);
                    o.z = fmaxf(o.z, 0.f);
                    o.w = fmaxf(o.w, 0.f);
                }
                *(float4*)(C + (size_t)gr * N + gc) = o;
            }
        }
    }
}

// ---------------- launch ----------------

static inline size_t rnd256(size_t x) { return (x + 255) & ~(size_t)255; }

static void launch_gemm(const float* A, const float* B, const float* bias, float* C,
                        int M, int N, int K, int relu, hipStream_t stream) {
    dim3 grid((N + 127) / 128, (M + 127) / 128);
    sgemm_kernel<<<grid, 256, 0, stream>>>(A, B, bias, C, M, N, K, relu);
}

extern "C" void kernel_launch(void* const* d_in, const int* in_sizes, int n_in,
                              void* d_out, int out_size, void* d_ws, size_t ws_size,
                              hipStream_t stream) {
    const float* x    = (const float*)d_in[0];
    const int*   src  = (const int*)d_in[1];
    const int*   dst  = (const int*)d_in[2];
    const float* eps1 = (const float*)d_in[3];
    const float* w1a  = (const float*)d_in[4];
    const float* w1b  = (const float*)d_in[5];
    const float* eps2 = (const float*)d_in[6];
    const float* w2a  = (const float*)d_in[7];
    const float* w2b  = (const float*)d_in[8];
    const float* fc_w = (const float*)d_in[9];
    const float* fc_b = (const float*)d_in[10];
    float* out = (float*)d_out;

    // workspace layout
    char* w = (char*)d_ws;
    int* deg  = (int*)w; w += rnd256(sizeof(int) * (size_t)N_NODES);        // also cursor
    int* off  = (int*)w; w += rnd256(sizeof(int) * (size_t)(N_NODES + 1));
    int* bsum = (int*)w; w += rnd256(sizeof(int) * 1024);
    int* csr  = (int*)w; w += rnd256(sizeof(int) * (size_t)N_EDGES);
    float* buf1 = (float*)w; w += rnd256(sizeof(float) * (size_t)N_NODES * DIM_H);
    float* buf2 = (float*)w; w += rnd256(sizeof(float) * (size_t)N_NODES * DIM_H);

    const int nb = (N_NODES + 255) / 256;   // 391 blocks for scan

    // ---- CSR build (shared by both layers) ----
    k_zero_int<<<nb, 256, 0, stream>>>(deg, N_NODES);
    k_hist<<<(N_EDGES + 255) / 256, 256, 0, stream>>>(dst, deg, N_EDGES);
    k_scan1<<<nb, 256, 0, stream>>>(deg, off, bsum, N_NODES);
    k_scan2<<<1, 512, 0, stream>>>(bsum, nb);
    k_scan3<<<nb, 256, 0, stream>>>(off, bsum, N_NODES);
    k_cursor<<<nb, 256, 0, stream>>>(off, deg, N_NODES);   // deg reused as cursor
    k_scatter<<<(N_EDGES + 255) / 256, 256, 0, stream>>>(src, dst, deg, csr, N_EDGES);

    // ---- layer 1 ----
    // rst1 = (1+eps1)*x + agg(x)   [N,128] -> buf1
    k_agg<DIM_IN><<<(N_NODES * 64 + 255) / 256, 256, 0, stream>>>(x, off, csr, eps1, buf1, N_NODES);
    // t1 = relu(rst1 @ w1a)        [N,256] -> buf2
    launch_gemm(buf1, w1a, nullptr, buf2, N_NODES, DIM_H, DIM_IN, 1, stream);
    // h1 = relu(t1 @ w1b)          [N,256] -> buf1
    launch_gemm(buf2, w1b, nullptr, buf1, N_NODES, DIM_H, DIM_H, 1, stream);

    // ---- layer 2 ----
    // rst2 = (1+eps2)*h1 + agg(h1) [N,256] -> buf2
    k_agg<DIM_H><<<(N_NODES * 64 + 255) / 256, 256, 0, stream>>>(buf1, off, csr, eps2, buf2, N_NODES);
    // t2 = relu(rst2 @ w2a)        [N,256] -> buf1
    launch_gemm(buf2, w2a, nullptr, buf1, N_NODES, DIM_H, DIM_H, 1, stream);
    // h2 = relu(t2 @ w2b)          [N,256] -> buf2
    launch_gemm(buf1, w2b, nullptr, buf2, N_NODES, DIM_H, DIM_H, 1, stream);

    // ---- classifier ----
    // out = h2 @ fc_w + fc_b       [N,40]
    launch_gemm(buf2, fc_w, fc_b, out, N_NODES, DIM_C, DIM_H, 0, stream);
}

// Round 2
// 812.960 us; speedup vs baseline: 1.7788x; 1.7788x over previous
//
#include <hip/hip_runtime.h>

#define N_NODES 100000
#define N_EDGES 1600000
#define DIM_IN  128
#define DIM_H   256
#define DIM_C   40

typedef unsigned short bf16_t;
typedef __attribute__((ext_vector_type(8))) short short8;
typedef __attribute__((ext_vector_type(4))) float f32x4;

// ---- bf16 helpers (RNE) ----
__device__ __forceinline__ bf16_t f2b(float f) {
    unsigned int u = __float_as_uint(f);
    unsigned int r = (u + 0x7fffu + ((u >> 16) & 1u)) >> 16;
    return (bf16_t)r;
}
__device__ __forceinline__ float b2f(unsigned int h16) {
    return __uint_as_float(h16 << 16);
}

__device__ __forceinline__ void gl_lds16(const void* gsrc, void* ldst) {
    __builtin_amdgcn_global_load_lds(
        (const __attribute__((address_space(1))) void*)gsrc,
        (__attribute__((address_space(3))) void*)ldst,
        16, 0, 0);
}

// ---------------- CSR build ----------------

__global__ void k_zero_int(int* __restrict__ p, int n) {
    int i = blockIdx.x * 256 + threadIdx.x;
    if (i < n) p[i] = 0;
}

__global__ void k_hist(const int* __restrict__ dst, int* __restrict__ deg, int e) {
    int i = blockIdx.x * 256 + threadIdx.x;
    if (i < e) atomicAdd(&deg[dst[i]], 1);
}

__global__ void k_scan1(const int* __restrict__ deg, int* __restrict__ off,
                        int* __restrict__ bsum, int n) {
    __shared__ int s[256];
    int i = blockIdx.x * 256 + threadIdx.x;
    int v = (i < n) ? deg[i] : 0;
    s[threadIdx.x] = v;
    __syncthreads();
    #pragma unroll
    for (int d = 1; d < 256; d <<= 1) {
        int t = (threadIdx.x >= d) ? s[threadIdx.x - d] : 0;
        __syncthreads();
        s[threadIdx.x] += t;
        __syncthreads();
    }
    if (i < n) off[i + 1] = s[threadIdx.x];
    if (threadIdx.x == 255) bsum[blockIdx.x] = s[255];
}

__global__ void k_scan2(int* __restrict__ bsum, int nb) {
    __shared__ int s[512];
    int v = ((int)threadIdx.x < nb) ? bsum[threadIdx.x] : 0;
    s[threadIdx.x] = v;
    __syncthreads();
    #pragma unroll
    for (int d = 1; d < 512; d <<= 1) {
        int t = (threadIdx.x >= d) ? s[threadIdx.x - d] : 0;
        __syncthreads();
        s[threadIdx.x] += t;
        __syncthreads();
    }
    if ((int)threadIdx.x < nb) bsum[threadIdx.x] = s[threadIdx.x];
}

__global__ void k_scan3(int* __restrict__ off, const int* __restrict__ bsum, int n) {
    int i = blockIdx.x * 256 + threadIdx.x;
    if (blockIdx.x > 0 && i < n) off[i + 1] += bsum[blockIdx.x - 1];
    if (i == 0) off[0] = 0;
}

__global__ void k_cursor(const int* __restrict__ off, int* __restrict__ cur, int n) {
    int i = blockIdx.x * 256 + threadIdx.x;
    if (i < n) cur[i] = off[i];
}

__global__ void k_scatter(const int* __restrict__ src, const int* __restrict__ dst,
                          int* __restrict__ cur, int* __restrict__ csr, int e) {
    int i = blockIdx.x * 256 + threadIdx.x;
    if (i < e) {
        int u = dst[i];
        int p = atomicAdd(&cur[u], 1);
        csr[p] = src[i];
    }
}

// ---------------- converts ----------------

// fp32 -> bf16 elementwise, vectorized x4
__global__ void k_cvt4(const float* __restrict__ in, bf16_t* __restrict__ out, int n4) {
    int i = blockIdx.x * 256 + threadIdx.x;
    if (i < n4) {
        float4 v = ((const float4*)in)[i];
        ushort4 o;
        o.x = f2b(v.x); o.y = f2b(v.y); o.z = f2b(v.z); o.w = f2b(v.w);
        ((ushort4*)out)[i] = o;
    }
}

// transpose+convert weights: in [K][N] fp32 -> out [Npad][K] bf16 (rows >= N zero)
__global__ void k_wt(const float* __restrict__ in, bf16_t* __restrict__ out,
                     int K, int N, int Npad) {
    int k = blockIdx.x * 256 + threadIdx.x;
    int n = blockIdx.y;
    if (k < K) {
        float v = (n < N) ? in[(size_t)k * N + n] : 0.f;
        out[(size_t)n * K + k] = f2b(v);
    }
}

// ---------------- aggregation (bf16 rows, fp32 accumulate, bf16 out) ----------------
// one wave per node; D=128: 2 elems/lane (uint), D=256: 4 elems/lane (uint2)

template <int D>
__global__ void k_agg_b(const bf16_t* __restrict__ h, const int* __restrict__ off,
                        const int* __restrict__ csr, const float* __restrict__ eps_p,
                        bf16_t* __restrict__ rst, int n) {
    constexpr int V = D / 64;  // 2 or 4
    int gid = blockIdx.x * blockDim.x + threadIdx.x;
    int u = gid >> 6;
    int lane = gid & 63;
    if (u >= n) return;

    float acc[V];
    #pragma unroll
    for (int j = 0; j < V; j++) acc[j] = 0.f;

    int r0 = off[u], r1 = off[u + 1];
    for (int r = r0; r < r1; r++) {
        int s = csr[r];
        const bf16_t* row = h + (size_t)s * D + lane * V;
        if constexpr (V == 2) {
            unsigned int v = *(const unsigned int*)row;
            acc[0] += b2f(v & 0xffffu);
            acc[1] += b2f(v >> 16);
        } else {
            uint2 v = *(const uint2*)row;
            acc[0] += b2f(v.x & 0xffffu);
            acc[1] += b2f(v.x >> 16);
            acc[2] += b2f(v.y & 0xffffu);
            acc[3] += b2f(v.y >> 16);
        }
    }
    float ep = 1.0f + eps_p[0];
    const bf16_t* xrow = h + (size_t)u * D + lane * V;
    bf16_t* orow = rst + (size_t)u * D + lane * V;
    if constexpr (V == 2) {
        unsigned int v = *(const unsigned int*)xrow;
        float o0 = ep * b2f(v & 0xffffu) + acc[0];
        float o1 = ep * b2f(v >> 16) + acc[1];
        unsigned int ov = (unsigned int)f2b(o0) | ((unsigned int)f2b(o1) << 16);
        *(unsigned int*)orow = ov;
    } else {
        uint2 v = *(const uint2*)xrow;
        float o0 = ep * b2f(v.x & 0xffffu) + acc[0];
        float o1 = ep * b2f(v.x >> 16) + acc[1];
        float o2 = ep * b2f(v.y & 0xffffu) + acc[2];
        float o3 = ep * b2f(v.y >> 16) + acc[3];
        uint2 ov;
        ov.x = (unsigned int)f2b(o0) | ((unsigned int)f2b(o1) << 16);
        ov.y = (unsigned int)f2b(o2) | ((unsigned int)f2b(o3) << 16);
        *(uint2*)orow = ov;
    }
}

// ---------------- MFMA bf16 GEMM (m97 structure) ----------------
// C[M,Nst] = op(A[M,K] @ Bt[Npad,K]^T), A row-major bf16, Bt row-major bf16 ("B^T")
// 128x128 tile, BK=32, 256 threads = 4 waves, each wave 64x64 via 4x4 of 16x16x32 MFMA.

template <typename OUT, bool RELU, bool BIAS>
__global__ __launch_bounds__(256) void gemm_bt(
    const bf16_t* __restrict__ A, const bf16_t* __restrict__ Bt,
    const float* __restrict__ bias, OUT* __restrict__ C,
    int M, int K, int Nst)
{
    __shared__ __align__(16) bf16_t As[128 * 32];
    __shared__ __align__(16) bf16_t Bs[128 * 32];

    int tid = threadIdx.x;
    int wave = tid >> 6, lane = tid & 63;
    int l15 = lane & 15, quad = lane >> 4;
    int bm = blockIdx.y * 128, bn = blockIdx.x * 128;
    int wm = (wave >> 1) * 64, wn = (wave & 1) * 64;

    f32x4 acc[4][4];
    #pragma unroll
    for (int i = 0; i < 4; i++)
        #pragma unroll
        for (int j = 0; j < 4; j++) acc[i][j] = 0.f;

    for (int k0 = 0; k0 < K; k0 += 32) {
        // stage A and Bt tiles: 128 rows x 32 k each, 16B (8 bf16) segments
        #pragma unroll
        for (int iss = 0; iss < 2; iss++) {
            int s = iss * 256 + wave * 64 + lane;   // 0..511
            int row = s >> 2;                        // 0..127
            int k8 = (s & 3) * 8;                    // 0,8,16,24
            int ldsoff = (iss * 256 + wave * 64) * 8;  // wave-uniform base (ushort idx)

            int grA = bm + row; if (grA >= M) grA = M - 1;
            gl_lds16(A + (size_t)grA * K + k0 + k8, &As[ldsoff]);

            int grB = bn + row;   // Bt padded: always valid
            gl_lds16(Bt + (size_t)grB * K + k0 + k8, &Bs[ldsoff]);
        }
        __syncthreads();

        short8 af[4], bfv[4];
        #pragma unroll
        for (int i = 0; i < 4; i++)
            af[i] = *(const short8*)&As[(wm + i * 16 + l15) * 32 + quad * 8];
        #pragma unroll
        for (int j = 0; j < 4; j++)
            bfv[j] = *(const short8*)&Bs[(wn + j * 16 + l15) * 32 + quad * 8];

        #pragma unroll
        for (int i = 0; i < 4; i++)
            #pragma unroll
            for (int j = 0; j < 4; j++)
                acc[i][j] = __builtin_amdgcn_mfma_f32_16x16x32_bf16(af[i], bfv[j], acc[i][j], 0, 0, 0);
        __syncthreads();
    }

    // epilogue: D row = quad*4 + reg, col = l15
    #pragma unroll
    for (int j = 0; j < 4; j++) {
        int col = bn + wn + j * 16 + l15;
        if (col >= Nst) continue;
        float bv = BIAS ? bias[col] : 0.f;
        #pragma unroll
        for (int i = 0; i < 4; i++) {
            #pragma unroll
            for (int r = 0; r < 4; r++) {
                int rowg = bm + wm + i * 16 + quad * 4 + r;
                if (rowg < M) {
                    float v = acc[i][j][r] + bv;
                    if (RELU) v = fmaxf(v, 0.f);
                    if constexpr (sizeof(OUT) == 2) {
                        C[(size_t)rowg * Nst + col] = (OUT)f2b(v);
                    } else {
                        C[(size_t)rowg * Nst + col] = (OUT)v;
                    }
                }
            }
        }
    }
}

// ---------------- launch ----------------

static inline size_t rnd256(size_t x) { return (x + 255) & ~(size_t)255; }

extern "C" void kernel_launch(void* const* d_in, const int* in_sizes, int n_in,
                              void* d_out, int out_size, void* d_ws, size_t ws_size,
                              hipStream_t stream) {
    const float* x    = (const float*)d_in[0];
    const int*   src  = (const int*)d_in[1];
    const int*   dst  = (const int*)d_in[2];
    const float* eps1 = (const float*)d_in[3];
    const float* w1a  = (const float*)d_in[4];
    const float* w1b  = (const float*)d_in[5];
    const float* eps2 = (const float*)d_in[6];
    const float* w2a  = (const float*)d_in[7];
    const float* w2b  = (const float*)d_in[8];
    const float* fc_w = (const float*)d_in[9];
    const float* fc_b = (const float*)d_in[10];
    float* out = (float*)d_out;

    // workspace layout
    char* w = (char*)d_ws;
    int* deg  = (int*)w; w += rnd256(sizeof(int) * (size_t)N_NODES);
    int* off  = (int*)w; w += rnd256(sizeof(int) * (size_t)(N_NODES + 1));
    int* bsum = (int*)w; w += rnd256(sizeof(int) * 1024);
    int* csr  = (int*)w; w += rnd256(sizeof(int) * (size_t)N_EDGES);
    bf16_t* w1a_t = (bf16_t*)w; w += rnd256(2 * (size_t)DIM_H * DIM_IN);   // [256][128]
    bf16_t* w1b_t = (bf16_t*)w; w += rnd256(2 * (size_t)DIM_H * DIM_H);    // [256][256]
    bf16_t* w2a_t = (bf16_t*)w; w += rnd256(2 * (size_t)DIM_H * DIM_H);
    bf16_t* w2b_t = (bf16_t*)w; w += rnd256(2 * (size_t)DIM_H * DIM_H);
    bf16_t* fc_t  = (bf16_t*)w; w += rnd256(2 * (size_t)128 * DIM_H);      // [128][256] padded
    bf16_t* R12 = (bf16_t*)w; w += rnd256(2 * (size_t)N_NODES * DIM_H);    // 51.2 MB
    bf16_t* R3  = (bf16_t*)w; w += rnd256(2 * (size_t)N_NODES * DIM_H);    // 51.2 MB

    bf16_t* xb   = R12;                          // [N][128]
    bf16_t* rst1 = R12 + (size_t)N_NODES * DIM_IN;  // [N][128]

    const int nb = (N_NODES + 255) / 256;

    // ---- CSR build ----
    k_zero_int<<<nb, 256, 0, stream>>>(deg, N_NODES);
    k_hist<<<(N_EDGES + 255) / 256, 256, 0, stream>>>(dst, deg, N_EDGES);
    k_scan1<<<nb, 256, 0, stream>>>(deg, off, bsum, N_NODES);
    k_scan2<<<1, 512, 0, stream>>>(bsum, nb);
    k_scan3<<<nb, 256, 0, stream>>>(off, bsum, N_NODES);
    k_cursor<<<nb, 256, 0, stream>>>(off, deg, N_NODES);
    k_scatter<<<(N_EDGES + 255) / 256, 256, 0, stream>>>(src, dst, deg, csr, N_EDGES);

    // ---- converts ----
    k_cvt4<<<(N_NODES * DIM_IN / 4 + 255) / 256, 256, 0, stream>>>(x, xb, N_NODES * DIM_IN / 4);
    { dim3 g((DIM_IN + 255) / 256, DIM_H);  k_wt<<<g, 256, 0, stream>>>(w1a, w1a_t, DIM_IN, DIM_H, DIM_H); }
    { dim3 g((DIM_H + 255) / 256, DIM_H);   k_wt<<<g, 256, 0, stream>>>(w1b, w1b_t, DIM_H, DIM_H, DIM_H); }
    { dim3 g((DIM_H + 255) / 256, DIM_H);   k_wt<<<g, 256, 0, stream>>>(w2a, w2a_t, DIM_H, DIM_H, DIM_H); }
    { dim3 g((DIM_H + 255) / 256, DIM_H);   k_wt<<<g, 256, 0, stream>>>(w2b, w2b_t, DIM_H, DIM_H, DIM_H); }
    { dim3 g((DIM_H + 255) / 256, 128);     k_wt<<<g, 256, 0, stream>>>(fc_w, fc_t, DIM_H, DIM_C, 128); }

    const int agg_blocks = (N_NODES * 64 + 255) / 256;
    dim3 g2(2, (N_NODES + 127) / 128);   // N=256 GEMMs
    dim3 g1(1, (N_NODES + 127) / 128);   // fc GEMM

    // ---- layer 1 ----
    k_agg_b<DIM_IN><<<agg_blocks, 256, 0, stream>>>(xb, off, csr, eps1, rst1, N_NODES);
    // t1 = relu(rst1 @ w1a) -> R3
    gemm_bt<bf16_t, true, false><<<g2, 256, 0, stream>>>(rst1, w1a_t, nullptr, R3, N_NODES, DIM_IN, DIM_H);
    // h1 = relu(t1 @ w1b) -> R12
    gemm_bt<bf16_t, true, false><<<g2, 256, 0, stream>>>(R3, w1b_t, nullptr, R12, N_NODES, DIM_H, DIM_H);

    // ---- layer 2 ----
    // rst2 = agg(h1) -> R3
    k_agg_b<DIM_H><<<agg_blocks, 256, 0, stream>>>(R12, off, csr, eps2, R3, N_NODES);
    // t2 = relu(rst2 @ w2a) -> R12
    gemm_bt<bf16_t, true, false><<<g2, 256, 0, stream>>>(R3, w2a_t, nullptr, R12, N_NODES, DIM_H, DIM_H);
    // h2 = relu(t2 @ w2b) -> R3
    gemm_bt<bf16_t, true, false><<<g2, 256, 0, stream>>>(R12, w2b_t, nullptr, R3, N_NODES, DIM_H, DIM_H);

    // ---- classifier: out = h2 @ fc_w + fc_b ----
    gemm_bt<float, false, true><<<g1, 256, 0, stream>>>(R3, fc_t, fc_b, out, N_NODES, DIM_H, DIM_C);
}

// Round 3
// 676.706 us; speedup vs baseline: 2.1370x; 1.2013x over previous
//
#include <hip/hip_runtime.h>

#define N_NODES 100000
#define N_EDGES 1600000
#define DIM_IN  128
#define DIM_H   256
#define DIM_C   40

typedef unsigned short bf16_t;
typedef __attribute__((ext_vector_type(8))) short short8;
typedef __attribute__((ext_vector_type(4))) float f32x4;

// ---- bf16 helpers (RNE) ----
__device__ __forceinline__ bf16_t f2b(float f) {
    unsigned int u = __float_as_uint(f);
    unsigned int r = (u + 0x7fffu + ((u >> 16) & 1u)) >> 16;
    return (bf16_t)r;
}
__device__ __forceinline__ float b2f(unsigned int h16) {
    return __uint_as_float(h16 << 16);
}

__device__ __forceinline__ void gl_lds16(const void* gsrc, void* ldst) {
    __builtin_amdgcn_global_load_lds(
        (const __attribute__((address_space(1))) void*)gsrc,
        (__attribute__((address_space(3))) void*)ldst,
        16, 0, 0);
}

// ---------------- CSR build ----------------

__global__ void k_zero_int(int* __restrict__ p, int n) {
    int i = blockIdx.x * 256 + threadIdx.x;
    if (i < n) p[i] = 0;
}

__global__ void k_hist(const int* __restrict__ dst, int* __restrict__ deg, int e) {
    int i = blockIdx.x * 256 + threadIdx.x;
    if (i < e) atomicAdd(&deg[dst[i]], 1);
}

__global__ void k_scan1(const int* __restrict__ deg, int* __restrict__ off,
                        int* __restrict__ bsum, int n) {
    __shared__ int s[256];
    int i = blockIdx.x * 256 + threadIdx.x;
    int v = (i < n) ? deg[i] : 0;
    s[threadIdx.x] = v;
    __syncthreads();
    #pragma unroll
    for (int d = 1; d < 256; d <<= 1) {
        int t = (threadIdx.x >= d) ? s[threadIdx.x - d] : 0;
        __syncthreads();
        s[threadIdx.x] += t;
        __syncthreads();
    }
    if (i < n) off[i + 1] = s[threadIdx.x];
    if (threadIdx.x == 255) bsum[blockIdx.x] = s[255];
}

__global__ void k_scan2(int* __restrict__ bsum, int nb) {
    __shared__ int s[512];
    int v = ((int)threadIdx.x < nb) ? bsum[threadIdx.x] : 0;
    s[threadIdx.x] = v;
    __syncthreads();
    #pragma unroll
    for (int d = 1; d < 512; d <<= 1) {
        int t = (threadIdx.x >= d) ? s[threadIdx.x - d] : 0;
        __syncthreads();
        s[threadIdx.x] += t;
        __syncthreads();
    }
    if ((int)threadIdx.x < nb) bsum[threadIdx.x] = s[threadIdx.x];
}

// also writes cursor copy (cur = final exclusive offsets)
__global__ void k_scan3(int* __restrict__ off, const int* __restrict__ bsum,
                        int* __restrict__ cur, int n) {
    int i = blockIdx.x * 256 + threadIdx.x;
    if (i < n) {
        int v = off[i + 1] + ((blockIdx.x > 0) ? bsum[blockIdx.x - 1] : 0);
        off[i + 1] = v;
    }
    if (i == 0) off[0] = 0;
    __syncthreads();
    // exclusive offset for node i is off[i]; recompute locally to avoid extra pass:
    // cur[i] = off[i]  (off[i] final only if its block already ran; instead derive:
    //   off[i] final = inclusive(i-1)+base; we just read again below safely since
    //   we wrote off[i+1] above and off[i] was written by thread i-1 of same or prev block)
    // To stay order-safe, compute cur from the same data we already have:
    //   thread i holds final off[i+1]; shift via separate kernel is simpler — but we
    //   can write cur[i+1] region: cur[i+1] = off[i+1]; cur[0]=0 by thread 0.
    if (i < n - 1) cur[i + 1] = off[i + 1];
    if (i == 0) cur[0] = 0;
}

__global__ void k_scatter(const int* __restrict__ src, const int* __restrict__ dst,
                          int* __restrict__ cur, int* __restrict__ csr, int e) {
    int i = blockIdx.x * 256 + threadIdx.x;
    if (i < e) {
        int u = dst[i];
        int p = atomicAdd(&cur[u], 1);
        csr[p] = src[i];
    }
}

// ---------------- converts ----------------

__global__ void k_cvt4(const float* __restrict__ in, bf16_t* __restrict__ out, int n4) {
    int i = blockIdx.x * 256 + threadIdx.x;
    if (i < n4) {
        float4 v = ((const float4*)in)[i];
        ushort4 o;
        o.x = f2b(v.x); o.y = f2b(v.y); o.z = f2b(v.z); o.w = f2b(v.w);
        ((ushort4*)out)[i] = o;
    }
}

// transpose+convert weights: in [K][N] fp32 -> out [Npad][K] bf16 (rows >= N zero)
__global__ void k_wt(const float* __restrict__ in, bf16_t* __restrict__ out,
                     int K, int N, int Npad) {
    int k = blockIdx.x * 256 + threadIdx.x;
    int n = blockIdx.y;
    if (k < K) {
        float v = (n < N) ? in[(size_t)k * N + n] : 0.f;
        out[(size_t)n * K + k] = f2b(v);
    }
}

// ---------------- aggregation (bf16 rows, fp32 accumulate, bf16 out) ----------------
// one wave per node; batched edge loop (8 rows in flight) for memory-level parallelism

template <int D>
__global__ void k_agg_b(const bf16_t* __restrict__ h, const int* __restrict__ off,
                        const int* __restrict__ csr, const float* __restrict__ eps_p,
                        bf16_t* __restrict__ rst, int n) {
    constexpr int V = D / 64;  // 2 or 4
    int gid = blockIdx.x * blockDim.x + threadIdx.x;
    int u = gid >> 6;
    int lane = gid & 63;
    if (u >= n) return;

    float acc[V];
    #pragma unroll
    for (int j = 0; j < V; j++) acc[j] = 0.f;

    int r0 = off[u], r1 = off[u + 1];
    int r = r0;

    if constexpr (V == 2) {
        for (; r + 8 <= r1; r += 8) {
            int s[8];
            #pragma unroll
            for (int t = 0; t < 8; t++) s[t] = csr[r + t];
            unsigned int v[8];
            #pragma unroll
            for (int t = 0; t < 8; t++)
                v[t] = *(const unsigned int*)(h + (size_t)s[t] * D + lane * 2);
            #pragma unroll
            for (int t = 0; t < 8; t++) {
                acc[0] += b2f(v[t] & 0xffffu);
                acc[1] += b2f(v[t] >> 16);
            }
        }
        for (; r < r1; r++) {
            int s = csr[r];
            unsigned int v = *(const unsigned int*)(h + (size_t)s * D + lane * 2);
            acc[0] += b2f(v & 0xffffu);
            acc[1] += b2f(v >> 16);
        }
    } else {
        for (; r + 8 <= r1; r += 8) {
            int s[8];
            #pragma unroll
            for (int t = 0; t < 8; t++) s[t] = csr[r + t];
            uint2 v[8];
            #pragma unroll
            for (int t = 0; t < 8; t++)
                v[t] = *(const uint2*)(h + (size_t)s[t] * D + lane * 4);
            #pragma unroll
            for (int t = 0; t < 8; t++) {
                acc[0] += b2f(v[t].x & 0xffffu);
                acc[1] += b2f(v[t].x >> 16);
                acc[2] += b2f(v[t].y & 0xffffu);
                acc[3] += b2f(v[t].y >> 16);
            }
        }
        for (; r < r1; r++) {
            int s = csr[r];
            uint2 v = *(const uint2*)(h + (size_t)s * D + lane * 4);
            acc[0] += b2f(v.x & 0xffffu);
            acc[1] += b2f(v.x >> 16);
            acc[2] += b2f(v.y & 0xffffu);
            acc[3] += b2f(v.y >> 16);
        }
    }

    float ep = 1.0f + eps_p[0];
    const bf16_t* xrow = h + (size_t)u * D + lane * V;
    bf16_t* orow = rst + (size_t)u * D + lane * V;
    if constexpr (V == 2) {
        unsigned int v = *(const unsigned int*)xrow;
        float o0 = ep * b2f(v & 0xffffu) + acc[0];
        float o1 = ep * b2f(v >> 16) + acc[1];
        *(unsigned int*)orow = (unsigned int)f2b(o0) | ((unsigned int)f2b(o1) << 16);
    } else {
        uint2 v = *(const uint2*)xrow;
        float o0 = ep * b2f(v.x & 0xffffu) + acc[0];
        float o1 = ep * b2f(v.x >> 16) + acc[1];
        float o2 = ep * b2f(v.y & 0xffffu) + acc[2];
        float o3 = ep * b2f(v.y >> 16) + acc[3];
        uint2 ov;
        ov.x = (unsigned int)f2b(o0) | ((unsigned int)f2b(o1) << 16);
        ov.y = (unsigned int)f2b(o2) | ((unsigned int)f2b(o3) << 16);
        *(uint2*)orow = ov;
    }
}

// ---------------- MFMA bf16 GEMM (m97 structure) ----------------

template <typename OUT, bool RELU, bool BIAS>
__global__ __launch_bounds__(256) void gemm_bt(
    const bf16_t* __restrict__ A, const bf16_t* __restrict__ Bt,
    const float* __restrict__ bias, OUT* __restrict__ C,
    int M, int K, int Nst)
{
    __shared__ __align__(16) bf16_t As[128 * 32];
    __shared__ __align__(16) bf16_t Bs[128 * 32];

    int tid = threadIdx.x;
    int wave = tid >> 6, lane = tid & 63;
    int l15 = lane & 15, quad = lane >> 4;
    int bm = blockIdx.y * 128, bn = blockIdx.x * 128;
    int wm = (wave >> 1) * 64, wn = (wave & 1) * 64;

    f32x4 acc[4][4];
    #pragma unroll
    for (int i = 0; i < 4; i++)
        #pragma unroll
        for (int j = 0; j < 4; j++) acc[i][j] = 0.f;

    for (int k0 = 0; k0 < K; k0 += 32) {
        #pragma unroll
        for (int iss = 0; iss < 2; iss++) {
            int s = iss * 256 + wave * 64 + lane;
            int row = s >> 2;
            int k8 = (s & 3) * 8;
            int ldsoff = (iss * 256 + wave * 64) * 8;

            int grA = bm + row; if (grA >= M) grA = M - 1;
            gl_lds16(A + (size_t)grA * K + k0 + k8, &As[ldsoff]);

            int grB = bn + row;
            gl_lds16(Bt + (size_t)grB * K + k0 + k8, &Bs[ldsoff]);
        }
        __syncthreads();

        short8 af[4], bfv[4];
        #pragma unroll
        for (int i = 0; i < 4; i++)
            af[i] = *(const short8*)&As[(wm + i * 16 + l15) * 32 + quad * 8];
        #pragma unroll
        for (int j = 0; j < 4; j++)
            bfv[j] = *(const short8*)&Bs[(wn + j * 16 + l15) * 32 + quad * 8];

        #pragma unroll
        for (int i = 0; i < 4; i++)
            #pragma unroll
            for (int j = 0; j < 4; j++)
                acc[i][j] = __builtin_amdgcn_mfma_f32_16x16x32_bf16(af[i], bfv[j], acc[i][j], 0, 0, 0);
        __syncthreads();
    }

    #pragma unroll
    for (int j = 0; j < 4; j++) {
        int col = bn + wn + j * 16 + l15;
        if (col >= Nst) continue;
        float bv = BIAS ? bias[col] : 0.f;
        #pragma unroll
        for (int i = 0; i < 4; i++) {
            #pragma unroll
            for (int r = 0; r < 4; r++) {
                int rowg = bm + wm + i * 16 + quad * 4 + r;
                if (rowg < M) {
                    float v = acc[i][j][r] + bv;
                    if (RELU) v = fmaxf(v, 0.f);
                    if constexpr (sizeof(OUT) == 2) {
                        C[(size_t)rowg * Nst + col] = (OUT)f2b(v);
                    } else {
                        C[(size_t)rowg * Nst + col] = (OUT)v;
                    }
                }
            }
        }
    }
}

// ---------------- launch ----------------

static inline size_t rnd256(size_t x) { return (x + 255) & ~(size_t)255; }

extern "C" void kernel_launch(void* const* d_in, const int* in_sizes, int n_in,
                              void* d_out, int out_size, void* d_ws, size_t ws_size,
                              hipStream_t stream) {
    const float* x    = (const float*)d_in[0];
    const int*   src  = (const int*)d_in[1];
    const int*   dst  = (const int*)d_in[2];
    const float* eps1 = (const float*)d_in[3];
    const float* w1a  = (const float*)d_in[4];
    const float* w1b  = (const float*)d_in[5];
    const float* eps2 = (const float*)d_in[6];
    const float* w2a  = (const float*)d_in[7];
    const float* w2b  = (const float*)d_in[8];
    const float* fc_w = (const float*)d_in[9];
    const float* fc_b = (const float*)d_in[10];
    float* out = (float*)d_out;

    char* w = (char*)d_ws;
    int* deg  = (int*)w; w += rnd256(sizeof(int) * (size_t)N_NODES);
    int* off  = (int*)w; w += rnd256(sizeof(int) * (size_t)(N_NODES + 1));
    int* bsum = (int*)w; w += rnd256(sizeof(int) * 1024);
    int* csr  = (int*)w; w += rnd256(sizeof(int) * (size_t)N_EDGES);
    bf16_t* w1a_t = (bf16_t*)w; w += rnd256(2 * (size_t)DIM_H * DIM_IN);
    bf16_t* w1b_t = (bf16_t*)w; w += rnd256(2 * (size_t)DIM_H * DIM_H);
    bf16_t* w2a_t = (bf16_t*)w; w += rnd256(2 * (size_t)DIM_H * DIM_H);
    bf16_t* w2b_t = (bf16_t*)w; w += rnd256(2 * (size_t)DIM_H * DIM_H);
    bf16_t* fc_t  = (bf16_t*)w; w += rnd256(2 * (size_t)128 * DIM_H);
    bf16_t* R12 = (bf16_t*)w; w += rnd256(2 * (size_t)N_NODES * DIM_H);
    bf16_t* R3  = (bf16_t*)w; w += rnd256(2 * (size_t)N_NODES * DIM_H);

    bf16_t* xb   = R12;
    bf16_t* rst1 = R12 + (size_t)N_NODES * DIM_IN;

    const int nb = (N_NODES + 255) / 256;

    // ---- CSR build ----
    k_zero_int<<<nb, 256, 0, stream>>>(deg, N_NODES);
    k_hist<<<(N_EDGES + 255) / 256, 256, 0, stream>>>(dst, deg, N_EDGES);
    k_scan1<<<nb, 256, 0, stream>>>(deg, off, bsum, N_NODES);
    k_scan2<<<1, 512, 0, stream>>>(bsum, nb);
    k_scan3<<<nb, 256, 0, stream>>>(off, bsum, deg /*cur*/, N_NODES);
    k_scatter<<<(N_EDGES + 255) / 256, 256, 0, stream>>>(src, dst, deg, csr, N_EDGES);

    // ---- converts ----
    k_cvt4<<<(N_NODES * DIM_IN / 4 + 255) / 256, 256, 0, stream>>>(x, xb, N_NODES * DIM_IN / 4);
    { dim3 g((DIM_IN + 255) / 256, DIM_H);  k_wt<<<g, 256, 0, stream>>>(w1a, w1a_t, DIM_IN, DIM_H, DIM_H); }
    { dim3 g((DIM_H + 255) / 256, DIM_H);   k_wt<<<g, 256, 0, stream>>>(w1b, w1b_t, DIM_H, DIM_H, DIM_H); }
    { dim3 g((DIM_H + 255) / 256, DIM_H);   k_wt<<<g, 256, 0, stream>>>(w2a, w2a_t, DIM_H, DIM_H, DIM_H); }
    { dim3 g((DIM_H + 255) / 256, DIM_H);   k_wt<<<g, 256, 0, stream>>>(w2b, w2b_t, DIM_H, DIM_H, DIM_H); }
    { dim3 g((DIM_H + 255) / 256, 128);     k_wt<<<g, 256, 0, stream>>>(fc_w, fc_t, DIM_H, DIM_C, 128); }

    const int agg_blocks = (N_NODES * 64 + 255) / 256;
    dim3 g2(2, (N_NODES + 127) / 128);
    dim3 g1(1, (N_NODES + 127) / 128);

    // ---- layer 1 ----
    k_agg_b<DIM_IN><<<agg_blocks, 256, 0, stream>>>(xb, off, csr, eps1, rst1, N_NODES);
    gemm_bt<bf16_t, true, false><<<g2, 256, 0, stream>>>(rst1, w1a_t, nullptr, R3, N_NODES, DIM_IN, DIM_H);
    gemm_bt<bf16_t, true, false><<<g2, 256, 0, stream>>>(R3, w1b_t, nullptr, R12, N_NODES, DIM_H, DIM_H);

    // ---- layer 2 ----
    k_agg_b<DIM_H><<<agg_blocks, 256, 0, stream>>>(R12, off, csr, eps2, R3, N_NODES);
    gemm_bt<bf16_t, true, false><<<g2, 256, 0, stream>>>(R3, w2a_t, nullptr, R12, N_NODES, DIM_H, DIM_H);
    gemm_bt<bf16_t, true, false><<<g2, 256, 0, stream>>>(R12, w2b_t, nullptr, R3, N_NODES, DIM_H, DIM_H);

    // ---- classifier ----
    gemm_bt<float, false, true><<<g1, 256, 0, stream>>>(R3, fc_t, fc_b, out, N_NODES, DIM_H, DIM_C);
}

// Round 4
// 538.547 us; speedup vs baseline: 2.6852x; 1.2565x over previous
//
#include <hip/hip_runtime.h>

#define N_NODES 100000
#define N_EDGES 1600000
#define DIM_IN  128
#define DIM_H   256
#define DIM_C   40

#define NB   391     // buckets of 256 nodes: ceil(100000/256)
#define NBLK 391     // edge chunks of 4096: ceil(1600000/4096)
#define CHUNK 4096

typedef unsigned short bf16_t;
typedef __attribute__((ext_vector_type(8))) short short8;
typedef __attribute__((ext_vector_type(4))) float f32x4;

// ---- bf16 helpers (RNE) ----
__device__ __forceinline__ bf16_t f2b(float f) {
    unsigned int u = __float_as_uint(f);
    unsigned int r = (u + 0x7fffu + ((u >> 16) & 1u)) >> 16;
    return (bf16_t)r;
}
__device__ __forceinline__ float b2f(unsigned int h16) {
    return __uint_as_float(h16 << 16);
}

__device__ __forceinline__ void gl_lds16(const void* gsrc, void* ldst) {
    __builtin_amdgcn_global_load_lds(
        (const __attribute__((address_space(1))) void*)gsrc,
        (__attribute__((address_space(3))) void*)ldst,
        16, 0, 0);
}

// ---------------- CSR build, two-phase binned ----------------

// A1: per-chunk histogram over 391 buckets (LDS atomics only)
__global__ void k_bhist(const int* __restrict__ dst, int* __restrict__ cnt2, int e) {
    __shared__ int h[NB];
    int t = threadIdx.x, blk = blockIdx.x;
    for (int i = t; i < NB; i += 256) h[i] = 0;
    __syncthreads();
    int base = blk * CHUNK;
    int end = min(base + CHUNK, e);
    for (int i = base + t; i < end; i += 256)
        atomicAdd(&h[dst[i] >> 8], 1);
    __syncthreads();
    for (int i = t; i < NB; i += 256) cnt2[blk * NB + i] = h[i];
}

// B1: per-bucket exclusive scan over chunk counts (column of cnt2) + bucket total
__global__ void k_bscanA(const int* __restrict__ cnt2, int* __restrict__ basep,
                         int* __restrict__ btot) {
    __shared__ int s[512];
    int t = threadIdx.x, b = blockIdx.x;
    int v = (t < NBLK) ? cnt2[t * NB + b] : 0;
    s[t] = v;
    __syncthreads();
    #pragma unroll
    for (int d = 1; d < 512; d <<= 1) {
        int tv = (t >= d) ? s[t - d] : 0;
        __syncthreads();
        s[t] += tv;
        __syncthreads();
    }
    if (t < NBLK) basep[t * NB + b] = s[t] - v;   // exclusive
    if (t == 511) btot[b] = s[511];
}

// B2: single-block exclusive scan of bucket totals -> boff[0..NB]
__global__ void k_bscan2(const int* __restrict__ btot, int* __restrict__ boff) {
    __shared__ int s[512];
    int t = threadIdx.x;
    int v = (t < NB) ? btot[t] : 0;
    s[t] = v;
    __syncthreads();
    #pragma unroll
    for (int d = 1; d < 512; d <<= 1) {
        int tv = (t >= d) ? s[t - d] : 0;
        __syncthreads();
        s[t] += tv;
        __syncthreads();
    }
    if (t < NB) boff[t] = s[t] - v;
    if (t == NB - 1) boff[NB] = s[t];
}

// A3: binned scatter of (src,dst) pairs into ebuf (LDS cursors)
__global__ void k_bscatter(const int* __restrict__ src, const int* __restrict__ dst,
                           const int* __restrict__ basep, const int* __restrict__ boff,
                           int2* __restrict__ ebuf, int e) {
    __shared__ int cur[NB];
    int t = threadIdx.x, blk = blockIdx.x;
    for (int i = t; i < NB; i += 256) cur[i] = basep[blk * NB + i] + boff[i];
    __syncthreads();
    int base = blk * CHUNK;
    int end = min(base + CHUNK, e);
    for (int i = base + t; i < end; i += 256) {
        int sv = src[i], dv = dst[i];
        int pos = atomicAdd(&cur[dv >> 8], 1);
        ebuf[pos] = make_int2(sv, dv);
    }
}

// Bh: per-bucket node-degree histogram (LDS atomics), writes deg
__global__ void k_bh(const int2* __restrict__ ebuf, const int* __restrict__ boff,
                     int* __restrict__ deg) {
    __shared__ int h[256];
    int t = threadIdx.x, b = blockIdx.x;
    h[t] = 0;
    __syncthreads();
    int e0 = boff[b], e1 = boff[b + 1];
    int node0 = b << 8;
    for (int i = e0 + t; i < e1; i += 256)
        atomicAdd(&h[ebuf[i].y - node0], 1);
    __syncthreads();
    int node = node0 + t;
    if (node < N_NODES) deg[node] = h[t];
}

// scan deg -> off (3 small kernels, unchanged structure)
__global__ void k_scan1(const int* __restrict__ deg, int* __restrict__ off,
                        int* __restrict__ bsum, int n) {
    __shared__ int s[256];
    int i = blockIdx.x * 256 + threadIdx.x;
    int v = (i < n) ? deg[i] : 0;
    s[threadIdx.x] = v;
    __syncthreads();
    #pragma unroll
    for (int d = 1; d < 256; d <<= 1) {
        int t = (threadIdx.x >= d) ? s[threadIdx.x - d] : 0;
        __syncthreads();
        s[threadIdx.x] += t;
        __syncthreads();
    }
    if (i < n) off[i + 1] = s[threadIdx.x];
    if (threadIdx.x == 255) bsum[blockIdx.x] = s[255];
}

__global__ void k_scan2(int* __restrict__ bsum, int nb) {
    __shared__ int s[512];
    int v = ((int)threadIdx.x < nb) ? bsum[threadIdx.x] : 0;
    s[threadIdx.x] = v;
    __syncthreads();
    #pragma unroll
    for (int d = 1; d < 512; d <<= 1) {
        int t = (threadIdx.x >= d) ? s[threadIdx.x - d] : 0;
        __syncthreads();
        s[threadIdx.x] += t;
        __syncthreads();
    }
    if ((int)threadIdx.x < nb) bsum[threadIdx.x] = s[threadIdx.x];
}

__global__ void k_scan3(int* __restrict__ off, const int* __restrict__ bsum, int n) {
    int i = blockIdx.x * 256 + threadIdx.x;
    if (blockIdx.x > 0 && i < n) off[i + 1] += bsum[blockIdx.x - 1];
    if (i == 0) off[0] = 0;
}

// Final: per-bucket exact scatter with LDS cursors; csr writes stay in a ~16KB region
__global__ void k_fscatter(const int2* __restrict__ ebuf, const int* __restrict__ boff,
                           const int* __restrict__ off, int* __restrict__ csr) {
    __shared__ int cur[256];
    int t = threadIdx.x, b = blockIdx.x;
    int node0 = b << 8;
    int node = node0 + t;
    cur[t] = (node < N_NODES) ? off[node] : 0;
    __syncthreads();
    int e0 = boff[b], e1 = boff[b + 1];
    for (int i = e0 + t; i < e1; i += 256) {
        int2 p = ebuf[i];
        int pos = atomicAdd(&cur[p.y - node0], 1);
        csr[pos] = p.x;
    }
}

// ---------------- converts ----------------

__global__ void k_cvt4(const float* __restrict__ in, bf16_t* __restrict__ out, int n4) {
    int i = blockIdx.x * 256 + threadIdx.x;
    if (i < n4) {
        float4 v = ((const float4*)in)[i];
        ushort4 o;
        o.x = f2b(v.x); o.y = f2b(v.y); o.z = f2b(v.z); o.w = f2b(v.w);
        ((ushort4*)out)[i] = o;
    }
}

__global__ void k_wt(const float* __restrict__ in, bf16_t* __restrict__ out,
                     int K, int N, int Npad) {
    int k = blockIdx.x * 256 + threadIdx.x;
    int n = blockIdx.y;
    if (k < K) {
        float v = (n < N) ? in[(size_t)k * N + n] : 0.f;
        out[(size_t)n * K + k] = f2b(v);
    }
}

// ---------------- aggregation (bf16 rows, fp32 accumulate, bf16 out) ----------------
// one wave per node; batched edge loop (8 rows in flight)

template <int D>
__global__ void k_agg_b(const bf16_t* __restrict__ h, const int* __restrict__ off,
                        const int* __restrict__ csr, const float* __restrict__ eps_p,
                        bf16_t* __restrict__ rst, int n) {
    constexpr int V = D / 64;  // 2 or 4
    int gid = blockIdx.x * blockDim.x + threadIdx.x;
    int u = gid >> 6;
    int lane = gid & 63;
    if (u >= n) return;

    float acc[V];
    #pragma unroll
    for (int j = 0; j < V; j++) acc[j] = 0.f;

    int r0 = off[u], r1 = off[u + 1];
    int r = r0;

    if constexpr (V == 2) {
        for (; r + 8 <= r1; r += 8) {
            int s[8];
            #pragma unroll
            for (int t = 0; t < 8; t++) s[t] = csr[r + t];
            unsigned int v[8];
            #pragma unroll
            for (int t = 0; t < 8; t++)
                v[t] = *(const unsigned int*)(h + (size_t)s[t] * D + lane * 2);
            #pragma unroll
            for (int t = 0; t < 8; t++) {
                acc[0] += b2f(v[t] & 0xffffu);
                acc[1] += b2f(v[t] >> 16);
            }
        }
        for (; r < r1; r++) {
            int s = csr[r];
            unsigned int v = *(const unsigned int*)(h + (size_t)s * D + lane * 2);
            acc[0] += b2f(v & 0xffffu);
            acc[1] += b2f(v >> 16);
        }
    } else {
        for (; r + 8 <= r1; r += 8) {
            int s[8];
            #pragma unroll
            for (int t = 0; t < 8; t++) s[t] = csr[r + t];
            uint2 v[8];
            #pragma unroll
            for (int t = 0; t < 8; t++)
                v[t] = *(const uint2*)(h + (size_t)s[t] * D + lane * 4);
            #pragma unroll
            for (int t = 0; t < 8; t++) {
                acc[0] += b2f(v[t].x & 0xffffu);
                acc[1] += b2f(v[t].x >> 16);
                acc[2] += b2f(v[t].y & 0xffffu);
                acc[3] += b2f(v[t].y >> 16);
            }
        }
        for (; r < r1; r++) {
            int s = csr[r];
            uint2 v = *(const uint2*)(h + (size_t)s * D + lane * 4);
            acc[0] += b2f(v.x & 0xffffu);
            acc[1] += b2f(v.x >> 16);
            acc[2] += b2f(v.y & 0xffffu);
            acc[3] += b2f(v.y >> 16);
        }
    }

    float ep = 1.0f + eps_p[0];
    const bf16_t* xrow = h + (size_t)u * D + lane * V;
    bf16_t* orow = rst + (size_t)u * D + lane * V;
    if constexpr (V == 2) {
        unsigned int v = *(const unsigned int*)xrow;
        float o0 = ep * b2f(v & 0xffffu) + acc[0];
        float o1 = ep * b2f(v >> 16) + acc[1];
        *(unsigned int*)orow = (unsigned int)f2b(o0) | ((unsigned int)f2b(o1) << 16);
    } else {
        uint2 v = *(const uint2*)xrow;
        float o0 = ep * b2f(v.x & 0xffffu) + acc[0];
        float o1 = ep * b2f(v.x >> 16) + acc[1];
        float o2 = ep * b2f(v.y & 0xffffu) + acc[2];
        float o3 = ep * b2f(v.y >> 16) + acc[3];
        uint2 ov;
        ov.x = (unsigned int)f2b(o0) | ((unsigned int)f2b(o1) << 16);
        ov.y = (unsigned int)f2b(o2) | ((unsigned int)f2b(o3) << 16);
        *(uint2*)orow = ov;
    }
}

// ---------------- MFMA bf16 GEMM (m97 structure) ----------------

template <typename OUT, bool RELU, bool BIAS>
__global__ __launch_bounds__(256) void gemm_bt(
    const bf16_t* __restrict__ A, const bf16_t* __restrict__ Bt,
    const float* __restrict__ bias, OUT* __restrict__ C,
    int M, int K, int Nst)
{
    __shared__ __align__(16) bf16_t As[128 * 32];
    __shared__ __align__(16) bf16_t Bs[128 * 32];

    int tid = threadIdx.x;
    int wave = tid >> 6, lane = tid & 63;
    int l15 = lane & 15, quad = lane >> 4;
    int bm = blockIdx.y * 128, bn = blockIdx.x * 128;
    int wm = (wave >> 1) * 64, wn = (wave & 1) * 64;

    f32x4 acc[4][4];
    #pragma unroll
    for (int i = 0; i < 4; i++)
        #pragma unroll
        for (int j = 0; j < 4; j++) acc[i][j] = 0.f;

    for (int k0 = 0; k0 < K; k0 += 32) {
        #pragma unroll
        for (int iss = 0; iss < 2; iss++) {
            int s = iss * 256 + wave * 64 + lane;
            int row = s >> 2;
            int k8 = (s & 3) * 8;
            int ldsoff = (iss * 256 + wave * 64) * 8;

            int grA = bm + row; if (grA >= M) grA = M - 1;
            gl_lds16(A + (size_t)grA * K + k0 + k8, &As[ldsoff]);

            int grB = bn + row;
            gl_lds16(Bt + (size_t)grB * K + k0 + k8, &Bs[ldsoff]);
        }
        __syncthreads();

        short8 af[4], bfv[4];
        #pragma unroll
        for (int i = 0; i < 4; i++)
            af[i] = *(const short8*)&As[(wm + i * 16 + l15) * 32 + quad * 8];
        #pragma unroll
        for (int j = 0; j < 4; j++)
            bfv[j] = *(const short8*)&Bs[(wn + j * 16 + l15) * 32 + quad * 8];

        #pragma unroll
        for (int i = 0; i < 4; i++)
            #pragma unroll
            for (int j = 0; j < 4; j++)
                acc[i][j] = __builtin_amdgcn_mfma_f32_16x16x32_bf16(af[i], bfv[j], acc[i][j], 0, 0, 0);
        __syncthreads();
    }

    #pragma unroll
    for (int j = 0; j < 4; j++) {
        int col = bn + wn + j * 16 + l15;
        if (col >= Nst) continue;
        float bv = BIAS ? bias[col] : 0.f;
        #pragma unroll
        for (int i = 0; i < 4; i++) {
            #pragma unroll
            for (int r = 0; r < 4; r++) {
                int rowg = bm + wm + i * 16 + quad * 4 + r;
                if (rowg < M) {
                    float v = acc[i][j][r] + bv;
                    if (RELU) v = fmaxf(v, 0.f);
                    if constexpr (sizeof(OUT) == 2) {
                        C[(size_t)rowg * Nst + col] = (OUT)f2b(v);
                    } else {
                        C[(size_t)rowg * Nst + col] = (OUT)v;
                    }
                }
            }
        }
    }
}

// ---------------- launch ----------------

static inline size_t rnd256(size_t x) { return (x + 255) & ~(size_t)255; }

extern "C" void kernel_launch(void* const* d_in, const int* in_sizes, int n_in,
                              void* d_out, int out_size, void* d_ws, size_t ws_size,
                              hipStream_t stream) {
    const float* x    = (const float*)d_in[0];
    const int*   src  = (const int*)d_in[1];
    const int*   dst  = (const int*)d_in[2];
    const float* eps1 = (const float*)d_in[3];
    const float* w1a  = (const float*)d_in[4];
    const float* w1b  = (const float*)d_in[5];
    const float* eps2 = (const float*)d_in[6];
    const float* w2a  = (const float*)d_in[7];
    const float* w2b  = (const float*)d_in[8];
    const float* fc_w = (const float*)d_in[9];
    const float* fc_b = (const float*)d_in[10];
    float* out = (float*)d_out;

    char* w = (char*)d_ws;
    int* deg  = (int*)w; w += rnd256(sizeof(int) * (size_t)N_NODES);
    int* off  = (int*)w; w += rnd256(sizeof(int) * (size_t)(N_NODES + 1));
    int* bsum = (int*)w; w += rnd256(sizeof(int) * 1024);
    int* csr  = (int*)w; w += rnd256(sizeof(int) * (size_t)N_EDGES);
    int* cnt2  = (int*)w; w += rnd256(sizeof(int) * (size_t)NBLK * NB);
    int* basep = (int*)w; w += rnd256(sizeof(int) * (size_t)NBLK * NB);
    int* btot  = (int*)w; w += rnd256(sizeof(int) * 512);
    int* boff  = (int*)w; w += rnd256(sizeof(int) * (NB + 1));
    bf16_t* w1a_t = (bf16_t*)w; w += rnd256(2 * (size_t)DIM_H * DIM_IN);
    bf16_t* w1b_t = (bf16_t*)w; w += rnd256(2 * (size_t)DIM_H * DIM_H);
    bf16_t* w2a_t = (bf16_t*)w; w += rnd256(2 * (size_t)DIM_H * DIM_H);
    bf16_t* w2b_t = (bf16_t*)w; w += rnd256(2 * (size_t)DIM_H * DIM_H);
    bf16_t* fc_t  = (bf16_t*)w; w += rnd256(2 * (size_t)128 * DIM_H);
    bf16_t* R12 = (bf16_t*)w; w += rnd256(2 * (size_t)N_NODES * DIM_H);
    bf16_t* R3  = (bf16_t*)w; w += rnd256(2 * (size_t)N_NODES * DIM_H);

    bf16_t* xb   = R12;
    bf16_t* rst1 = R12 + (size_t)N_NODES * DIM_IN;
    // ebuf (12.8 MB) aliases R3: dead once k_fscatter completes, before first GEMM writes R3
    int2* ebuf = (int2*)R3;

    const int nb = (N_NODES + 255) / 256;

    // ---- CSR build: two-phase binned ----
    k_bhist<<<NBLK, 256, 0, stream>>>(dst, cnt2, N_EDGES);
    k_bscanA<<<NB, 512, 0, stream>>>(cnt2, basep, btot);
    k_bscan2<<<1, 512, 0, stream>>>(btot, boff);
    k_bscatter<<<NBLK, 256, 0, stream>>>(src, dst, basep, boff, ebuf, N_EDGES);
    k_bh<<<NB, 256, 0, stream>>>(ebuf, boff, deg);
    k_scan1<<<nb, 256, 0, stream>>>(deg, off, bsum, N_NODES);
    k_scan2<<<1, 512, 0, stream>>>(bsum, nb);
    k_scan3<<<nb, 256, 0, stream>>>(off, bsum, N_NODES);
    k_fscatter<<<NB, 256, 0, stream>>>(ebuf, boff, off, csr);

    // ---- converts ----
    k_cvt4<<<(N_NODES * DIM_IN / 4 + 255) / 256, 256, 0, stream>>>(x, xb, N_NODES * DIM_IN / 4);
    { dim3 g((DIM_IN + 255) / 256, DIM_H);  k_wt<<<g, 256, 0, stream>>>(w1a, w1a_t, DIM_IN, DIM_H, DIM_H); }
    { dim3 g((DIM_H + 255) / 256, DIM_H);   k_wt<<<g, 256, 0, stream>>>(w1b, w1b_t, DIM_H, DIM_H, DIM_H); }
    { dim3 g((DIM_H + 255) / 256, DIM_H);   k_wt<<<g, 256, 0, stream>>>(w2a, w2a_t, DIM_H, DIM_H, DIM_H); }
    { dim3 g((DIM_H + 255) / 256, DIM_H);   k_wt<<<g, 256, 0, stream>>>(w2b, w2b_t, DIM_H, DIM_H, DIM_H); }
    { dim3 g((DIM_H + 255) / 256, 128);     k_wt<<<g, 256, 0, stream>>>(fc_w, fc_t, DIM_H, DIM_C, 128); }

    const int agg_blocks = (N_NODES * 64 + 255) / 256;
    dim3 g2(2, (N_NODES + 127) / 128);
    dim3 g1(1, (N_NODES + 127) / 128);

    // ---- layer 1 ----
    k_agg_b<DIM_IN><<<agg_blocks, 256, 0, stream>>>(xb, off, csr, eps1, rst1, N_NODES);
    gemm_bt<bf16_t, true, false><<<g2, 256, 0, stream>>>(rst1, w1a_t, nullptr, R3, N_NODES, DIM_IN, DIM_H);
    gemm_bt<bf16_t, true, false><<<g2, 256, 0, stream>>>(R3, w1b_t, nullptr, R12, N_NODES, DIM_H, DIM_H);

    // ---- layer 2 ----
    k_agg_b<DIM_H><<<agg_blocks, 256, 0, stream>>>(R12, off, csr, eps2, R3, N_NODES);
    gemm_bt<bf16_t, true, false><<<g2, 256, 0, stream>>>(R3, w2a_t, nullptr, R12, N_NODES, DIM_H, DIM_H);
    gemm_bt<bf16_t, true, false><<<g2, 256, 0, stream>>>(R12, w2b_t, nullptr, R3, N_NODES, DIM_H, DIM_H);

    // ---- classifier ----
    gemm_bt<float, false, true><<<g1, 256, 0, stream>>>(R3, fc_t, fc_b, out, N_NODES, DIM_H, DIM_C);
}

// Round 5
// 533.260 us; speedup vs baseline: 2.7118x; 1.0099x over previous
//
#include <hip/hip_runtime.h>

#define N_NODES 100000
#define N_EDGES 1600000
#define DIM_IN  128
#define DIM_H   256
#define DIM_C   40

#define NB   391     // buckets of 256 nodes: ceil(100000/256)
#define NBLK 391     // edge chunks of 4096: ceil(1600000/4096)
#define CHUNK 4096

typedef unsigned short bf16_t;
typedef __attribute__((ext_vector_type(8))) short short8;
typedef __attribute__((ext_vector_type(4))) float f32x4;

// ---- bf16 helpers (RNE) ----
__device__ __forceinline__ bf16_t f2b(float f) {
    unsigned int u = __float_as_uint(f);
    unsigned int r = (u + 0x7fffu + ((u >> 16) & 1u)) >> 16;
    return (bf16_t)r;
}
__device__ __forceinline__ float b2f(unsigned int h16) {
    return __uint_as_float(h16 << 16);
}

__device__ __forceinline__ void gl_lds16(const void* gsrc, void* ldst) {
    __builtin_amdgcn_global_load_lds(
        (const __attribute__((address_space(1))) void*)gsrc,
        (__attribute__((address_space(3))) void*)ldst,
        16, 0, 0);
}

// ---------------- CSR build, two-phase binned ----------------

__global__ void k_bhist(const int* __restrict__ dst, int* __restrict__ cnt2, int e) {
    __shared__ int h[NB];
    int t = threadIdx.x, blk = blockIdx.x;
    for (int i = t; i < NB; i += 256) h[i] = 0;
    __syncthreads();
    int base = blk * CHUNK;
    int end = min(base + CHUNK, e);
    for (int i = base + t; i < end; i += 256)
        atomicAdd(&h[dst[i] >> 8], 1);
    __syncthreads();
    for (int i = t; i < NB; i += 256) cnt2[blk * NB + i] = h[i];
}

__global__ void k_bscanA(const int* __restrict__ cnt2, int* __restrict__ basep,
                         int* __restrict__ btot) {
    __shared__ int s[512];
    int t = threadIdx.x, b = blockIdx.x;
    int v = (t < NBLK) ? cnt2[t * NB + b] : 0;
    s[t] = v;
    __syncthreads();
    #pragma unroll
    for (int d = 1; d < 512; d <<= 1) {
        int tv = (t >= d) ? s[t - d] : 0;
        __syncthreads();
        s[t] += tv;
        __syncthreads();
    }
    if (t < NBLK) basep[t * NB + b] = s[t] - v;
    if (t == 511) btot[b] = s[511];
}

__global__ void k_bscan2(const int* __restrict__ btot, int* __restrict__ boff) {
    __shared__ int s[512];
    int t = threadIdx.x;
    int v = (t < NB) ? btot[t] : 0;
    s[t] = v;
    __syncthreads();
    #pragma unroll
    for (int d = 1; d < 512; d <<= 1) {
        int tv = (t >= d) ? s[t - d] : 0;
        __syncthreads();
        s[t] += tv;
        __syncthreads();
    }
    if (t < NB) boff[t] = s[t] - v;
    if (t == NB - 1) boff[NB] = s[t];
}

__global__ void k_bscatter(const int* __restrict__ src, const int* __restrict__ dst,
                           const int* __restrict__ basep, const int* __restrict__ boff,
                           int2* __restrict__ ebuf, int e) {
    __shared__ int cur[NB];
    int t = threadIdx.x, blk = blockIdx.x;
    for (int i = t; i < NB; i += 256) cur[i] = basep[blk * NB + i] + boff[i];
    __syncthreads();
    int base = blk * CHUNK;
    int end = min(base + CHUNK, e);
    for (int i = base + t; i < end; i += 256) {
        int sv = src[i], dv = dst[i];
        int pos = atomicAdd(&cur[dv >> 8], 1);
        ebuf[pos] = make_int2(sv, dv);
    }
}

__global__ void k_bh(const int2* __restrict__ ebuf, const int* __restrict__ boff,
                     int* __restrict__ deg) {
    __shared__ int h[256];
    int t = threadIdx.x, b = blockIdx.x;
    h[t] = 0;
    __syncthreads();
    int e0 = boff[b], e1 = boff[b + 1];
    int node0 = b << 8;
    for (int i = e0 + t; i < e1; i += 256)
        atomicAdd(&h[ebuf[i].y - node0], 1);
    __syncthreads();
    int node = node0 + t;
    if (node < N_NODES) deg[node] = h[t];
}

__global__ void k_scan1(const int* __restrict__ deg, int* __restrict__ off,
                        int* __restrict__ bsum, int n) {
    __shared__ int s[256];
    int i = blockIdx.x * 256 + threadIdx.x;
    int v = (i < n) ? deg[i] : 0;
    s[threadIdx.x] = v;
    __syncthreads();
    #pragma unroll
    for (int d = 1; d < 256; d <<= 1) {
        int t = (threadIdx.x >= d) ? s[threadIdx.x - d] : 0;
        __syncthreads();
        s[threadIdx.x] += t;
        __syncthreads();
    }
    if (i < n) off[i + 1] = s[threadIdx.x];
    if (threadIdx.x == 255) bsum[blockIdx.x] = s[255];
}

__global__ void k_scan2(int* __restrict__ bsum, int nb) {
    __shared__ int s[512];
    int v = ((int)threadIdx.x < nb) ? bsum[threadIdx.x] : 0;
    s[threadIdx.x] = v;
    __syncthreads();
    #pragma unroll
    for (int d = 1; d < 512; d <<= 1) {
        int t = (threadIdx.x >= d) ? s[threadIdx.x - d] : 0;
        __syncthreads();
        s[threadIdx.x] += t;
        __syncthreads();
    }
    if ((int)threadIdx.x < nb) bsum[threadIdx.x] = s[threadIdx.x];
}

__global__ void k_scan3(int* __restrict__ off, const int* __restrict__ bsum, int n) {
    int i = blockIdx.x * 256 + threadIdx.x;
    if (blockIdx.x > 0 && i < n) off[i + 1] += bsum[blockIdx.x - 1];
    if (i == 0) off[0] = 0;
}

__global__ void k_fscatter(const int2* __restrict__ ebuf, const int* __restrict__ boff,
                           const int* __restrict__ off, int* __restrict__ csr) {
    __shared__ int cur[256];
    int t = threadIdx.x, b = blockIdx.x;
    int node0 = b << 8;
    int node = node0 + t;
    cur[t] = (node < N_NODES) ? off[node] : 0;
    __syncthreads();
    int e0 = boff[b], e1 = boff[b + 1];
    for (int i = e0 + t; i < e1; i += 256) {
        int2 p = ebuf[i];
        int pos = atomicAdd(&cur[p.y - node0], 1);
        csr[pos] = p.x;
    }
}

// ---------------- converts ----------------

__global__ void k_cvt4(const float* __restrict__ in, bf16_t* __restrict__ out, int n4) {
    int i = blockIdx.x * 256 + threadIdx.x;
    if (i < n4) {
        float4 v = ((const float4*)in)[i];
        ushort4 o;
        o.x = f2b(v.x); o.y = f2b(v.y); o.z = f2b(v.z); o.w = f2b(v.w);
        ((ushort4*)out)[i] = o;
    }
}

__global__ void k_wt(const float* __restrict__ in, bf16_t* __restrict__ out,
                     int K, int N, int Npad) {
    int k = blockIdx.x * 256 + threadIdx.x;
    int n = blockIdx.y;
    if (k < K) {
        float v = (n < N) ? in[(size_t)k * N + n] : 0.f;
        out[(size_t)n * K + k] = f2b(v);
    }
}

// ---------------- aggregation (bf16 rows, fp32 accumulate, bf16 out) ----------------
// one wave per node; 16-deep clamp-masked edge batches (wave-uniform predicate, no
// lane divergence; clamped extra loads hit same line -> L1)

template <int D>
__global__ void k_agg_b(const bf16_t* __restrict__ h, const int* __restrict__ off,
                        const int* __restrict__ csr, const float* __restrict__ eps_p,
                        bf16_t* __restrict__ rst, int n) {
    constexpr int V = D / 64;  // 2 or 4
    int gid = blockIdx.x * blockDim.x + threadIdx.x;
    int u = gid >> 6;
    int lane = gid & 63;
    if (u >= n) return;

    float acc[V];
    #pragma unroll
    for (int j = 0; j < V; j++) acc[j] = 0.f;

    int r0 = off[u], r1 = off[u + 1];
    int lim = r1 - 1;

    for (int r = r0; r < r1; r += 16) {
        int s[16];
        #pragma unroll
        for (int t = 0; t < 16; t++) s[t] = csr[min(r + t, lim)];
        if constexpr (V == 2) {
            unsigned int v[16];
            #pragma unroll
            for (int t = 0; t < 16; t++)
                v[t] = *(const unsigned int*)(h + (size_t)s[t] * D + lane * 2);
            #pragma unroll
            for (int t = 0; t < 16; t++) {
                if (r + t < r1) {
                    acc[0] += b2f(v[t] & 0xffffu);
                    acc[1] += b2f(v[t] >> 16);
                }
            }
        } else {
            uint2 v[16];
            #pragma unroll
            for (int t = 0; t < 16; t++)
                v[t] = *(const uint2*)(h + (size_t)s[t] * D + lane * 4);
            #pragma unroll
            for (int t = 0; t < 16; t++) {
                if (r + t < r1) {
                    acc[0] += b2f(v[t].x & 0xffffu);
                    acc[1] += b2f(v[t].x >> 16);
                    acc[2] += b2f(v[t].y & 0xffffu);
                    acc[3] += b2f(v[t].y >> 16);
                }
            }
        }
    }

    float ep = 1.0f + eps_p[0];
    const bf16_t* xrow = h + (size_t)u * D + lane * V;
    bf16_t* orow = rst + (size_t)u * D + lane * V;
    if constexpr (V == 2) {
        unsigned int v = *(const unsigned int*)xrow;
        float o0 = ep * b2f(v & 0xffffu) + acc[0];
        float o1 = ep * b2f(v >> 16) + acc[1];
        *(unsigned int*)orow = (unsigned int)f2b(o0) | ((unsigned int)f2b(o1) << 16);
    } else {
        uint2 v = *(const uint2*)xrow;
        float o0 = ep * b2f(v.x & 0xffffu) + acc[0];
        float o1 = ep * b2f(v.x >> 16) + acc[1];
        float o2 = ep * b2f(v.y & 0xffffu) + acc[2];
        float o3 = ep * b2f(v.y >> 16) + acc[3];
        uint2 ov;
        ov.x = (unsigned int)f2b(o0) | ((unsigned int)f2b(o1) << 16);
        ov.y = (unsigned int)f2b(o2) | ((unsigned int)f2b(o3) << 16);
        *(uint2*)orow = ov;
    }
}

// ---------------- MFMA bf16 GEMM (m97 structure) ----------------

template <typename OUT, bool RELU, bool BIAS>
__global__ __launch_bounds__(256) void gemm_bt(
    const bf16_t* __restrict__ A, const bf16_t* __restrict__ Bt,
    const float* __restrict__ bias, OUT* __restrict__ C,
    int M, int K, int Nst)
{
    __shared__ __align__(16) bf16_t As[128 * 32];
    __shared__ __align__(16) bf16_t Bs[128 * 32];

    int tid = threadIdx.x;
    int wave = tid >> 6, lane = tid & 63;
    int l15 = lane & 15, quad = lane >> 4;
    int bm = blockIdx.y * 128, bn = blockIdx.x * 128;
    int wm = (wave >> 1) * 64, wn = (wave & 1) * 64;

    f32x4 acc[4][4];
    #pragma unroll
    for (int i = 0; i < 4; i++)
        #pragma unroll
        for (int j = 0; j < 4; j++) acc[i][j] = 0.f;

    for (int k0 = 0; k0 < K; k0 += 32) {
        #pragma unroll
        for (int iss = 0; iss < 2; iss++) {
            int s = iss * 256 + wave * 64 + lane;
            int row = s >> 2;
            int k8 = (s & 3) * 8;
            int ldsoff = (iss * 256 + wave * 64) * 8;

            int grA = bm + row; if (grA >= M) grA = M - 1;
            gl_lds16(A + (size_t)grA * K + k0 + k8, &As[ldsoff]);

            int grB = bn + row;
            gl_lds16(Bt + (size_t)grB * K + k0 + k8, &Bs[ldsoff]);
        }
        __syncthreads();

        short8 af[4], bfv[4];
        #pragma unroll
        for (int i = 0; i < 4; i++)
            af[i] = *(const short8*)&As[(wm + i * 16 + l15) * 32 + quad * 8];
        #pragma unroll
        for (int j = 0; j < 4; j++)
            bfv[j] = *(const short8*)&Bs[(wn + j * 16 + l15) * 32 + quad * 8];

        #pragma unroll
        for (int i = 0; i < 4; i++)
            #pragma unroll
            for (int j = 0; j < 4; j++)
                acc[i][j] = __builtin_amdgcn_mfma_f32_16x16x32_bf16(af[i], bfv[j], acc[i][j], 0, 0, 0);
        __syncthreads();
    }

    #pragma unroll
    for (int j = 0; j < 4; j++) {
        int col = bn + wn + j * 16 + l15;
        if (col >= Nst) continue;
        float bv = BIAS ? bias[col] : 0.f;
        #pragma unroll
        for (int i = 0; i < 4; i++) {
            #pragma unroll
            for (int r = 0; r < 4; r++) {
                int rowg = bm + wm + i * 16 + quad * 4 + r;
                if (rowg < M) {
                    float v = acc[i][j][r] + bv;
                    if (RELU) v = fmaxf(v, 0.f);
                    if constexpr (sizeof(OUT) == 2) {
                        C[(size_t)rowg * Nst + col] = (OUT)f2b(v);
                    } else {
                        C[(size_t)rowg * Nst + col] = (OUT)v;
                    }
                }
            }
        }
    }
}

// ---------------- launch ----------------

static inline size_t rnd256(size_t x) { return (x + 255) & ~(size_t)255; }

extern "C" void kernel_launch(void* const* d_in, const int* in_sizes, int n_in,
                              void* d_out, int out_size, void* d_ws, size_t ws_size,
                              hipStream_t stream) {
    const float* x    = (const float*)d_in[0];
    const int*   src  = (const int*)d_in[1];
    const int*   dst  = (const int*)d_in[2];
    const float* eps1 = (const float*)d_in[3];
    const float* w1a  = (const float*)d_in[4];
    const float* w1b  = (const float*)d_in[5];
    const float* eps2 = (const float*)d_in[6];
    const float* w2a  = (const float*)d_in[7];
    const float* w2b  = (const float*)d_in[8];
    const float* fc_w = (const float*)d_in[9];
    const float* fc_b = (const float*)d_in[10];
    float* out = (float*)d_out;

    char* w = (char*)d_ws;
    int* deg  = (int*)w; w += rnd256(sizeof(int) * (size_t)N_NODES);
    int* off  = (int*)w; w += rnd256(sizeof(int) * (size_t)(N_NODES + 1));
    int* bsum = (int*)w; w += rnd256(sizeof(int) * 1024);
    int* csr  = (int*)w; w += rnd256(sizeof(int) * (size_t)N_EDGES);
    int* cnt2  = (int*)w; w += rnd256(sizeof(int) * (size_t)NBLK * NB);
    int* basep = (int*)w; w += rnd256(sizeof(int) * (size_t)NBLK * NB);
    int* btot  = (int*)w; w += rnd256(sizeof(int) * 512);
    int* boff  = (int*)w; w += rnd256(sizeof(int) * (NB + 1));
    bf16_t* w1a_t = (bf16_t*)w; w += rnd256(2 * (size_t)DIM_H * DIM_IN);
    bf16_t* w1b_t = (bf16_t*)w; w += rnd256(2 * (size_t)DIM_H * DIM_H);
    bf16_t* w2a_t = (bf16_t*)w; w += rnd256(2 * (size_t)DIM_H * DIM_H);
    bf16_t* w2b_t = (bf16_t*)w; w += rnd256(2 * (size_t)DIM_H * DIM_H);
    bf16_t* fc_t  = (bf16_t*)w; w += rnd256(2 * (size_t)128 * DIM_H);
    bf16_t* R12 = (bf16_t*)w; w += rnd256(2 * (size_t)N_NODES * DIM_H);
    bf16_t* R3  = (bf16_t*)w; w += rnd256(2 * (size_t)N_NODES * DIM_H);

    bf16_t* xb   = R12;
    bf16_t* rst1 = R12 + (size_t)N_NODES * DIM_IN;
    int2* ebuf = (int2*)R3;   // dead before first GEMM writes R3

    const int nb = (N_NODES + 255) / 256;

    // ---- CSR build: two-phase binned ----
    k_bhist<<<NBLK, 256, 0, stream>>>(dst, cnt2, N_EDGES);
    k_bscanA<<<NB, 512, 0, stream>>>(cnt2, basep, btot);
    k_bscan2<<<1, 512, 0, stream>>>(btot, boff);
    k_bscatter<<<NBLK, 256, 0, stream>>>(src, dst, basep, boff, ebuf, N_EDGES);
    k_bh<<<NB, 256, 0, stream>>>(ebuf, boff, deg);
    k_scan1<<<nb, 256, 0, stream>>>(deg, off, bsum, N_NODES);
    k_scan2<<<1, 512, 0, stream>>>(bsum, nb);
    k_scan3<<<nb, 256, 0, stream>>>(off, bsum, N_NODES);
    k_fscatter<<<NB, 256, 0, stream>>>(ebuf, boff, off, csr);

    // ---- converts ----
    k_cvt4<<<(N_NODES * DIM_IN / 4 + 255) / 256, 256, 0, stream>>>(x, xb, N_NODES * DIM_IN / 4);
    { dim3 g((DIM_IN + 255) / 256, DIM_H);  k_wt<<<g, 256, 0, stream>>>(w1a, w1a_t, DIM_IN, DIM_H, DIM_H); }
    { dim3 g((DIM_H + 255) / 256, DIM_H);   k_wt<<<g, 256, 0, stream>>>(w1b, w1b_t, DIM_H, DIM_H, DIM_H); }
    { dim3 g((DIM_H + 255) / 256, DIM_H);   k_wt<<<g, 256, 0, stream>>>(w2a, w2a_t, DIM_H, DIM_H, DIM_H); }
    { dim3 g((DIM_H + 255) / 256, DIM_H);   k_wt<<<g, 256, 0, stream>>>(w2b, w2b_t, DIM_H, DIM_H, DIM_H); }
    { dim3 g((DIM_H + 255) / 256, 128);     k_wt<<<g, 256, 0, stream>>>(fc_w, fc_t, DIM_H, DIM_C, 128); }

    const int agg_blocks = (N_NODES * 64 + 255) / 256;
    dim3 g2(2, (N_NODES + 127) / 128);
    dim3 g1(1, (N_NODES + 127) / 128);

    // ---- layer 1 ----
    k_agg_b<DIM_IN><<<agg_blocks, 256, 0, stream>>>(xb, off, csr, eps1, rst1, N_NODES);
    gemm_bt<bf16_t, true, false><<<g2, 256, 0, stream>>>(rst1, w1a_t, nullptr, R3, N_NODES, DIM_IN, DIM_H);
    gemm_bt<bf16_t, true, false><<<g2, 256, 0, stream>>>(R3, w1b_t, nullptr, R12, N_NODES, DIM_H, DIM_H);

    // ---- layer 2 ----
    k_agg_b<DIM_H><<<agg_blocks, 256, 0, stream>>>(R12, off, csr, eps2, R3, N_NODES);
    gemm_bt<bf16_t, true, false><<<g2, 256, 0, stream>>>(R3, w2a_t, nullptr, R12, N_NODES, DIM_H, DIM_H);
    gemm_bt<bf16_t, true, false><<<g2, 256, 0, stream>>>(R12, w2b_t, nullptr, R3, N_NODES, DIM_H, DIM_H);

    // ---- classifier ----
    gemm_bt<float, false, true><<<g1, 256, 0, stream>>>(R3, fc_t, fc_b, out, N_NODES, DIM_H, DIM_C);
}